// Round 8
// baseline (286.611 us; speedup 1.0000x reference)
//
#include <hip/hip_runtime.h>
#include <math.h>

typedef __attribute__((ext_vector_type(4))) float f32x4;
typedef __attribute__((ext_vector_type(8))) short short8;

#define DEV __device__ __forceinline__

DEV short f2bf(float f){
  union { float f; unsigned u; } v; v.f = f;
  unsigned r = v.u + 0x7fffu + ((v.u >> 16) & 1u);
  return (short)(r >> 16);
}
DEV float bf2f(short s){
  union { unsigned u; float f; } v; v.u = ((unsigned)(unsigned short)s) << 16; return v.f;
}
DEV float exp2_hw(float x){ float r; asm("v_exp_f32 %0, %1" : "=v"(r) : "v"(x)); return r; }
DEV float rcp_hw(float x){ float r; asm("v_rcp_f32 %0, %1" : "=v"(r) : "v"(x)); return r; }
DEV unsigned cvtpk(float a, float b){
  unsigned r; asm("v_cvt_pk_bf16_f32 %0, %1, %2" : "=v"(r) : "v"(a), "v"(b)); return r;
}
DEV void gload_lds16(const short* src, short* lds){
  __builtin_amdgcn_global_load_lds(
      (const __attribute__((address_space(1))) void*)src,
      (__attribute__((address_space(3))) void*)lds, 16, 0, 0);
}

// ---------------- weight transpose + f32->bf16 ----------------
__global__ __launch_bounds__(256) void transpose_bf16_kernel(
    const float* __restrict__ W, short* __restrict__ Wt, int K, int N)
{
  __shared__ float tile[32][33];
  int nb = blockIdx.x * 32, kb = blockIdx.y * 32;
  int tx = threadIdx.x & 31, ty = threadIdx.x >> 5;   // ty 0..7
  #pragma unroll
  for (int i = ty; i < 32; i += 8)
    tile[i][tx] = W[(size_t)(kb + i) * N + nb + tx];
  __syncthreads();
  #pragma unroll
  for (int i = ty; i < 32; i += 8)
    Wt[(size_t)(nb + i) * K + kb + tx] = f2bf(tile[tx][i]);
}

// ---------------- layernorm: one row per WAVE (f32 in, bf16 out) ----------------
// COPYX: also copy the raw input row to xcopy (fuses the out[1]=x pass-through)
template<int COPYX>
__global__ __launch_bounds__(256) void ln_kernel(
    const float* __restrict__ x, const float* __restrict__ g,
    const float* __restrict__ b, short* __restrict__ out,
    float* __restrict__ xcopy)
{
  int row  = blockIdx.x * 4 + (threadIdx.x >> 6);
  int lane = threadIdx.x & 63;
  const float* xr = x + (size_t)row * 512 + lane * 8;
  f32x4 v0 = *(const f32x4*)(xr);
  f32x4 v1 = *(const f32x4*)(xr + 4);
  float s  = (v0[0]+v0[1]+v0[2]+v0[3]) + (v1[0]+v1[1]+v1[2]+v1[3]);
  float sq = (v0[0]*v0[0]+v0[1]*v0[1]+v0[2]*v0[2]+v0[3]*v0[3])
           + (v1[0]*v1[0]+v1[1]*v1[1]+v1[2]*v1[2]+v1[3]*v1[3]);
  #pragma unroll
  for (int off = 1; off < 64; off <<= 1) {
    s  += __shfl_xor(s, off);
    sq += __shfl_xor(sq, off);
  }
  float mu  = s * (1.0f / 512.0f);
  float var = sq * (1.0f / 512.0f) - mu * mu;
  float rstd = rsqrtf(var + 1e-5f);
  f32x4 g0 = *(const f32x4*)(g + lane * 8);
  f32x4 g1 = *(const f32x4*)(g + lane * 8 + 4);
  f32x4 b0 = *(const f32x4*)(b + lane * 8);
  f32x4 b1 = *(const f32x4*)(b + lane * 8 + 4);
  float o[8];
  #pragma unroll
  for (int j = 0; j < 4; ++j) o[j]     = (v0[j] - mu) * rstd * g0[j] + b0[j];
  #pragma unroll
  for (int j = 0; j < 4; ++j) o[4 + j] = (v1[j] - mu) * rstd * g1[j] + b1[j];
  uint4 pk;
  pk.x = cvtpk(o[0], o[1]); pk.y = cvtpk(o[2], o[3]);
  pk.z = cvtpk(o[4], o[5]); pk.w = cvtpk(o[6], o[7]);
  *(uint4*)(out + (size_t)row * 512 + lane * 8) = pk;
  if (COPYX) {
    float* xc = xcopy + (size_t)row * 512 + lane * 8;
    *(f32x4*)(xc)     = v0;
    *(f32x4*)(xc + 4) = v1;
  }
}

// ---------------- GEMM: C[M,N] = A[M,K] * Bt[N,K]^T  (bf16 in, f32 acc) ----------------
// BM in {128, 64}, BN=128, BK=32. 3-buffer ring, prefetch depth 2, counted vmcnt
// (T3+T4): raw s_barrier, never vmcnt(0) in steady state. Fragment-major LDS.
// EPI: 0 = plain -> bf16 ; 1 = +bias +resid -> f32 ; 2 = +bias, GELU -> bf16
// EPI: 3 = plain -> bf16 for cols<1024; cols>=1024 go ONLY to vt (LDS transpose)
template<int EPI, int BM, typename OutT>
__global__ __launch_bounds__(256) void gemm_bt_kernel(
    const short* __restrict__ A, const short* __restrict__ Bt,
    OutT* __restrict__ C, const float* __restrict__ bias,
    const float* __restrict__ resid, short* __restrict__ vt,
    int M, int N, int K)
{
  constexpr int MFR = BM / 32;                     // 16-row frags per wave (2 waves on M)
  constexpr int NFR = 4;                           // 16-col frags per wave (2 waves on N)
  constexpr int AI  = BM / 64;                     // A staging instrs per thread
  constexpr int BUF = BM * 32 + 128 * 32;          // shorts per ring buffer
  __shared__ __align__(16) short smem[3 * BUF];

  int tid = threadIdx.x;
  int lane = tid & 63, wid = tid >> 6;
  int l16 = lane & 15, lq = lane >> 4;

  // bijective XCD-aware swizzle (all grids are %8 == 0)
  int gx = gridDim.x;
  int nwg = gx * gridDim.y;
  int orig = blockIdx.y * gx + blockIdx.x;
  int swz = (orig & 7) * (nwg >> 3) + (orig >> 3);
  int bn = swz % gx, bm = swz / gx;

  int wm = wid >> 1, wn = wid & 1;

  // hoisted staging pointers (only +k0 varies per step)
  const short* gaP[AI];
  const short* gbP[2];
  #pragma unroll
  for (int i = 0; i < AI; ++i) {
    int gg = i * 4 + wid;
    gaP[i] = A + (size_t)(bm * BM + gg * 16 + l16) * K + lq * 8;
  }
  #pragma unroll
  for (int i = 0; i < 2; ++i) {
    int gg = i * 4 + wid;
    gbP[i] = Bt + (size_t)(bn * 128 + gg * 16 + l16) * K + lq * 8;
  }

  auto STAGE = [&](int bufi, int k0) {
    short* base = smem + bufi * BUF;
    #pragma unroll
    for (int i = 0; i < AI; ++i)
      gload_lds16(gaP[i] + k0, base + (i * 4 + wid) * 512);
    #pragma unroll
    for (int i = 0; i < 2; ++i)
      gload_lds16(gbP[i] + k0, base + BM * 32 + (i * 4 + wid) * 512);
  };

  f32x4 acc[MFR][NFR] = {};

  STAGE(0, 0);
  STAGE(1, 32);

  int nt = K >> 5;
  for (int t = 0; t < nt; ++t) {
    // wait: my stage-t loads done (only t+1's NSTG remain), then block-wide sync
    if (t + 1 < nt) {
      if constexpr (AI == 2) asm volatile("s_waitcnt vmcnt(4)" ::: "memory");
      else                   asm volatile("s_waitcnt vmcnt(3)" ::: "memory");
    } else {
      asm volatile("s_waitcnt vmcnt(0)" ::: "memory");
    }
    __builtin_amdgcn_s_barrier();
    __builtin_amdgcn_sched_barrier(0);
    if (t + 2 < nt) STAGE((t + 2) % 3, (t + 2) << 5);  // overwrites buf(t-1): safe post-barrier

    const short* base = smem + (t % 3) * BUF;
    short8 af[MFR], bfr[NFR];
    #pragma unroll
    for (int m = 0; m < MFR; ++m)
      af[m] = *(const short8*)(base + (wm * MFR + m) * 512 + lane * 8);
    #pragma unroll
    for (int n = 0; n < NFR; ++n)
      bfr[n] = *(const short8*)(base + BM * 32 + (wn * NFR + n) * 512 + lane * 8);
    __builtin_amdgcn_s_setprio(1);
    #pragma unroll
    for (int m = 0; m < MFR; ++m)
      #pragma unroll
      for (int n = 0; n < NFR; ++n)
        acc[m][n] = __builtin_amdgcn_mfma_f32_16x16x32_bf16(af[m], bfr[n], acc[m][n], 0, 0, 0);
    __builtin_amdgcn_s_setprio(0);
  }

  if (EPI == 3 && bn >= 8) {
    // ---- V columns: LDS transpose -> vt [bh][d][n], coalesced 16B stores ----
    __syncthreads();                       // all waves done with ring buffers
    short* T = smem;                       // 128*128 shorts = 32 KB
    #pragma unroll
    for (int m = 0; m < MFR; ++m)
      #pragma unroll
      for (int n = 0; n < NFR; ++n) {
        int c = wn * 64 + n * 16 + l16;            // local col (0..127)
        #pragma unroll
        for (int r = 0; r < 4; ++r) {
          int rowl = wm * 64 + m * 16 + lq * 4 + r;
          T[c * 128 + (rowl ^ ((c & 7) << 4))] = f2bf(acc[m][n][r]);
        }
      }
    __syncthreads();
    int b2 = bm >> 4;                      // batch (BM=128: 16 row-blocks per batch)
    int nnb = (bm & 15) * 128;             // token base within batch
    int tn = tid & 15;
    #pragma unroll
    for (int c8 = 0; c8 < 8; ++c8) {
      int c = c8 * 16 + (tid >> 4);
      short8 v = *(const short8*)(T + c * 128 + ((tn * 8) ^ ((c & 7) << 4)));
      if (tn & 1) {                        // nns swizzle: slot s <- element s^4
        short8 w;
        #pragma unroll
        for (int j = 0; j < 8; ++j) w[j] = v[j ^ 4];
        v = w;
      }
      int c2 = bn * 128 + c - 1024;        // h*64 + d
      int bh = b2 * 8 + (c2 >> 6);
      int d  = c2 & 63;
      *(short8*)(vt + ((size_t)(bh * 64 + d)) * 2048 + nnb + tn * 8) = v;
    }
    return;
  }

  // ---- standard epilogue: n innermost so same-line segments are adjacent ----
  float bv[NFR];
  #pragma unroll
  for (int n = 0; n < NFR; ++n)
    bv[n] = (EPI == 0 || EPI == 3) ? 0.0f : bias[bn * 128 + (wn * NFR + n) * 16 + l16];

  #pragma unroll
  for (int m = 0; m < MFR; ++m) {
    #pragma unroll
    for (int r = 0; r < 4; ++r) {
      int row = bm * BM + (wm * MFR + m) * 16 + lq * 4 + r;
      #pragma unroll
      for (int n = 0; n < NFR; ++n) {
        int col = bn * 128 + (wn * NFR + n) * 16 + l16;
        float v = acc[m][n][r];
        if (EPI == 1 || EPI == 2) v += bv[n];
        if (EPI == 2) v = 0.5f * v * (1.0f + erff(v * 0.70710678f));
        if (EPI == 1) v += resid[(size_t)row * N + col];
        if constexpr (sizeof(OutT) == 2)
          ((short*)C)[(size_t)row * N + col] = f2bf(v);
        else
          ((float*)C)[(size_t)row * N + col] = v;
      }
    }
  }
}

// ---------------- fused flash attention with diagonal mask (LSA) ----------------
// Direct-from-L2 structure: NO LDS, NO barriers — waves fully independent.
// K rows are single 128B lines in qkv; vt is fragment-major (nns swizzle baked in),
// so K/V MFMA fragments load per-lane via global_load_dwordx4 in exact order.
// Manual pipeline: V(t) issued before QK^T, K(t+1) issued before softmax.
// Swapped-operand S^T = mfma(K, Q); in-register softmax, fixed m=0 (scale bounded);
// cvt_pk + 2-round shfl butterfly hands P^T to PV as mfma(V^T, P^T) = O^T.
__global__ __launch_bounds__(256) void attn_kernel(
    const short* __restrict__ qkv, const short* __restrict__ vt,
    const float* __restrict__ temp_ptr, short* __restrict__ out)
{
  int tid = threadIdx.x;
  int lane = tid & 63, wid = tid >> 6;
  int l16 = lane & 15, lq = lane >> 4;
  int hi = lq >> 1, lq0 = lq & 1;

  int orig = blockIdx.y * 16 + blockIdx.x;     // nwg = 512
  int swz = (orig & 7) * 64 + (orig >> 3);
  int qb = swz & 15, bh = swz >> 4;
  int b = bh >> 3, h = bh & 7;

  const short* qbase = qkv + (size_t)b * 2048 * 1536 + h * 64;
  const short* kbase = qbase + 512;
  const short* vbase = vt + (size_t)bh * 64 * 2048;

  float scale = __expf(temp_ptr[0]) * 1.44269504f;   // fold log2(e): exp2 domain
  int q0 = qb * 128 + wid * 32;

  // Q fragments, pre-scaled
  short8 qfrag[2][2];
  #pragma unroll
  for (int qf = 0; qf < 2; ++qf) {
    int qrow = q0 + qf * 16 + l16;
    #pragma unroll
    for (int c = 0; c < 2; ++c) {
      short8 raw = *(const short8*)(qbase + (size_t)qrow * 1536 + c * 32 + lq * 8);
      short8 sc;
      #pragma unroll
      for (int j = 0; j < 8; ++j) sc[j] = f2bf(bf2f(raw[j]) * scale);
      qfrag[qf][c] = sc;
    }
  }

  // per-lane fragment base pointers
  const short* kp = kbase + (size_t)l16 * 1536 + lq * 8;  // + (k0+s*16)*1536 + c*32
  const short* vp = vbase + (size_t)l16 * 2048 + lq * 8;  // + (d*16)*2048 + k0 + c*32

  f32x4 accO[2][4] = {};
  float l[2] = {0.f, 0.f};

  // K prologue: tile 0 fragments
  short8 kf[4][2];
  #pragma unroll
  for (int s = 0; s < 4; ++s)
    #pragma unroll
    for (int c = 0; c < 2; ++c)
      kf[s][c] = *(const short8*)(kp + (size_t)(s * 16) * 1536 + c * 32);

  #pragma unroll 2
  for (int t = 0; t < 32; ++t) {
    int k0 = t * 64;

    // ---- V loads for this tile (latency hides under QK^T + softmax)
    short8 vfr[4][2];
    #pragma unroll
    for (int d = 0; d < 4; ++d)
      #pragma unroll
      for (int c = 0; c < 2; ++c)
        vfr[d][c] = *(const short8*)(vp + (size_t)(d * 16) * 2048 + k0 + c * 32);

    // ---- S^T = K Q^T : accS[qf][s] row=key s*16+lq*4+r, col=q=l16
    f32x4 accS[2][4] = {};
    #pragma unroll
    for (int s = 0; s < 4; ++s)
      #pragma unroll
      for (int qf = 0; qf < 2; ++qf) {
        accS[qf][s] = __builtin_amdgcn_mfma_f32_16x16x32_bf16(kf[s][0], qfrag[qf][0], accS[qf][s], 0, 0, 0);
        accS[qf][s] = __builtin_amdgcn_mfma_f32_16x16x32_bf16(kf[s][1], qfrag[qf][1], accS[qf][s], 0, 0, 0);
      }

    // ---- K prefetch for next tile (latency hides under softmax + PV)
    if (t + 1 < 32) {
      #pragma unroll
      for (int s = 0; s < 4; ++s)
        #pragma unroll
        for (int c = 0; c < 2; ++c)
          kf[s][c] = *(const short8*)(kp + (size_t)((t + 1) * 64 + s * 16) * 1536 + c * 32);
    }

    // ---- LSA diagonal mask: only one tile intersects this wave's q-range
    if ((q0 & ~63) == k0) {
      #pragma unroll
      for (int qf = 0; qf < 2; ++qf) {
        int qg = q0 + qf * 16 + l16;
        #pragma unroll
        for (int s = 0; s < 4; ++s)
          #pragma unroll
          for (int r = 0; r < 4; ++r)
            if (k0 + s * 16 + lq * 4 + r == qg) accS[qf][s][r] = -30000.f;
      }
    }

    // ---- exp2 (fixed m=0) + sum + pack + 2-round butterfly transpose -> pa[qf][c]
    short8 pa[2][2];
    #pragma unroll
    for (int qf = 0; qf < 2; ++qf) {
      float sum = 0.f;
      unsigned W[4][2];
      #pragma unroll
      for (int s = 0; s < 4; ++s) {
        float p0 = exp2_hw(accS[qf][s][0]);
        float p1 = exp2_hw(accS[qf][s][1]);
        float p2 = exp2_hw(accS[qf][s][2]);
        float p3 = exp2_hw(accS[qf][s][3]);
        sum += (p0 + p1) + (p2 + p3);
        W[s][0] = cvtpk(p0, p1);
        W[s][1] = cvtpk(p2, p3);
      }
      sum += __shfl_xor(sum, 16);
      sum += __shfl_xor(sum, 32);
      l[qf] += sum;

      unsigned K0[2], S0[2], K2[2], S2[2], R0[2], R2[2];
      #pragma unroll
      for (int w = 0; w < 2; ++w) {
        K0[w] = hi ? W[1][w] : W[0][w];
        S0[w] = hi ? W[0][w] : W[1][w];
        K2[w] = hi ? W[3][w] : W[2][w];
        S2[w] = hi ? W[2][w] : W[3][w];
      }
      #pragma unroll
      for (int w = 0; w < 2; ++w) {
        R0[w] = (unsigned)__shfl_xor((int)S0[w], 32);
        R2[w] = (unsigned)__shfl_xor((int)S2[w], 32);
      }
      bool sw = (hi != lq0);
      unsigned FA[2], FB[2], sA[2], sB[2], GA[2], GB[2];
      #pragma unroll
      for (int w = 0; w < 2; ++w) {
        sA[w] = sw ? K0[w] : R0[w];  FA[w] = sw ? R0[w] : K0[w];
        sB[w] = sw ? K2[w] : R2[w];  FB[w] = sw ? R2[w] : K2[w];
      }
      #pragma unroll
      for (int w = 0; w < 2; ++w) {
        GA[w] = (unsigned)__shfl_xor((int)sA[w], 16);
        GB[w] = (unsigned)__shfl_xor((int)sB[w], 16);
      }
      union { unsigned u[4]; short8 s8; } p0u, p1u;
      p0u.u[0] = FA[0]; p0u.u[1] = FA[1]; p0u.u[2] = GA[0]; p0u.u[3] = GA[1];
      p1u.u[0] = FB[0]; p1u.u[1] = FB[1]; p1u.u[2] = GB[0]; p1u.u[3] = GB[1];
      pa[qf][0] = p0u.s8;
      pa[qf][1] = p1u.s8;
    }

    // ---- O^T += V^T P^T
    #pragma unroll
    for (int qf = 0; qf < 2; ++qf)
      #pragma unroll
      for (int d = 0; d < 4; ++d) {
        accO[qf][d] = __builtin_amdgcn_mfma_f32_16x16x32_bf16(vfr[d][0], pa[qf][0], accO[qf][d], 0, 0, 0);
        accO[qf][d] = __builtin_amdgcn_mfma_f32_16x16x32_bf16(vfr[d][1], pa[qf][1], accO[qf][d], 0, 0, 0);
      }
  }

  // ---- epilogue: out[q][h*64+d] = accO^T / l  (8B packed stores)
  #pragma unroll
  for (int qf = 0; qf < 2; ++qf) {
    float inv = rcp_hw(l[qf]);
    int qg = q0 + qf * 16 + l16;
    size_t rowoff = (size_t)(b * 2048 + qg) * 512 + h * 64;
    #pragma unroll
    for (int d = 0; d < 4; ++d) {
      unsigned w0 = cvtpk(accO[qf][d][0] * inv, accO[qf][d][1] * inv);
      unsigned w1 = cvtpk(accO[qf][d][2] * inv, accO[qf][d][3] * inv);
      uint2 pk; pk.x = w0; pk.y = w1;
      *(uint2*)(out + rowoff + d * 16 + lq * 4) = pk;
    }
  }
}

// ---------------- launcher ----------------
extern "C" void kernel_launch(void* const* d_in, const int* in_sizes, int n_in,
                              void* d_out, int out_size, void* d_ws, size_t ws_size,
                              hipStream_t stream)
{
  const float* x    = (const float*)d_in[0];
  const float* ln1g = (const float*)d_in[1];
  const float* ln1b = (const float*)d_in[2];
  const float* Wqkv = (const float*)d_in[3];
  const float* temp = (const float*)d_in[4];
  const float* Wo   = (const float*)d_in[5];
  const float* bo   = (const float*)d_in[6];
  const float* ln2g = (const float*)d_in[7];
  const float* ln2b = (const float*)d_in[8];
  const float* W1   = (const float*)d_in[9];
  const float* b1   = (const float*)d_in[10];
  const float* W2   = (const float*)d_in[11];
  const float* b2   = (const float*)d_in[12];
  float* out = (float*)d_out;

  char* ws = (char*)d_ws;
  short* wqkv_t = (short*)(ws);                    // [1536][512] bf16
  short* wo_t   = (short*)(ws + 1572864);          // [512][512]
  short* w1_t   = (short*)(ws + 2097152);          // [2048][512]
  short* w2_t   = (short*)(ws + 4194304);          // [512][2048]
  short* h      = (short*)(ws + 6291456);          // [8192][512] bf16 (LN out, reused)
  short* qkv    = (short*)(ws + 14680064);         // [8192][1536] bf16
  short* attn   = (short*)(ws + 39845888);         // [8192][512] bf16
  float* y      = (float*)(ws + 48234496);         // [8192][512] f32 (written AFTER attn)
  short* vt     = (short*)(ws + 48234496);         // [32][64][2048] bf16 (dead once y written)
  short* t      = (short*)(ws + 14680064);         // [8192][2048] bf16 (reuses qkv+attn)
  // ws high-water: 65,011,712 bytes

  const int M = 8192;

  transpose_bf16_kernel<<<dim3(1536 / 32, 512 / 32),  256, 0, stream>>>(Wqkv, wqkv_t, 512, 1536);
  transpose_bf16_kernel<<<dim3(512 / 32, 512 / 32),   256, 0, stream>>>(Wo,   wo_t,   512, 512);
  transpose_bf16_kernel<<<dim3(2048 / 32, 512 / 32),  256, 0, stream>>>(W1,   w1_t,   512, 2048);
  transpose_bf16_kernel<<<dim3(512 / 32, 2048 / 32),  256, 0, stream>>>(W2,   w2_t,   2048, 512);

  // LN1 + fused x -> out[1] copy
  ln_kernel<1><<<M / 4, 256, 0, stream>>>(x, ln1g, ln1b, h, out + (size_t)M * 512);

  gemm_bt_kernel<3, 128, short><<<dim3(1536 / 128, M / 128), 256, 0, stream>>>(
      h, wqkv_t, qkv, nullptr, nullptr, vt, M, 1536, 512);

  attn_kernel<<<dim3(16, 32), 256, 0, stream>>>(qkv, vt, temp, attn);

  gemm_bt_kernel<1, 64, float><<<dim3(512 / 128, M / 64), 256, 0, stream>>>(
      attn, wo_t, y, bo, x, nullptr, M, 512, 512);

  ln_kernel<0><<<M / 4, 256, 0, stream>>>(y, ln2g, ln2b, h, nullptr);

  gemm_bt_kernel<2, 128, short><<<dim3(2048 / 128, M / 128), 256, 0, stream>>>(
      h, w1_t, t, b1, nullptr, nullptr, M, 2048, 512);

  gemm_bt_kernel<1, 64, float><<<dim3(512 / 128, M / 64), 256, 0, stream>>>(
      t, w2_t, out, b2, y, nullptr, M, 512, 2048);
}

// Round 9
// 210.077 us; speedup vs baseline: 1.3643x; 1.3643x over previous
//
#include <hip/hip_runtime.h>
#include <math.h>

typedef __attribute__((ext_vector_type(4))) float f32x4;
typedef __attribute__((ext_vector_type(8))) short short8;

#define DEV __device__ __forceinline__

DEV short f2bf(float f){
  union { float f; unsigned u; } v; v.f = f;
  unsigned r = v.u + 0x7fffu + ((v.u >> 16) & 1u);
  return (short)(r >> 16);
}
DEV float bf2f(short s){
  union { unsigned u; float f; } v; v.u = ((unsigned)(unsigned short)s) << 16; return v.f;
}
DEV float exp2_hw(float x){ float r; asm("v_exp_f32 %0, %1" : "=v"(r) : "v"(x)); return r; }
DEV float rcp_hw(float x){ float r; asm("v_rcp_f32 %0, %1" : "=v"(r) : "v"(x)); return r; }
DEV unsigned cvtpk(float a, float b){
  unsigned r; asm("v_cvt_pk_bf16_f32 %0, %1, %2" : "=v"(r) : "v"(a), "v"(b)); return r;
}
DEV void gload_lds16(const short* src, short* lds){
  __builtin_amdgcn_global_load_lds(
      (const __attribute__((address_space(1))) void*)src,
      (__attribute__((address_space(3))) void*)lds, 16, 0, 0);
}
DEV float gelu_fast(float v){
  // tanh-form GELU via exp2: |err| vs exact erf-GELU < 1e-3
  float u = v * (0.79788456f + 0.03567741f * v * v);
  float e = exp2_hw(u * 2.88539008f);          // e^{2u}
  float th = 1.0f - 2.0f * rcp_hw(e + 1.0f);   // tanh(u)
  return 0.5f * v * (1.0f + th);
}

// ---------------- weight transpose + f32->bf16 ----------------
__global__ __launch_bounds__(256) void transpose_bf16_kernel(
    const float* __restrict__ W, short* __restrict__ Wt, int K, int N)
{
  __shared__ float tile[32][33];
  int nb = blockIdx.x * 32, kb = blockIdx.y * 32;
  int tx = threadIdx.x & 31, ty = threadIdx.x >> 5;   // ty 0..7
  #pragma unroll
  for (int i = ty; i < 32; i += 8)
    tile[i][tx] = W[(size_t)(kb + i) * N + nb + tx];
  __syncthreads();
  #pragma unroll
  for (int i = ty; i < 32; i += 8)
    Wt[(size_t)(nb + i) * K + kb + tx] = f2bf(tile[tx][i]);
}

// ---------------- layernorm: one row per WAVE (f32 in, bf16 out) ----------------
// COPYX: also copy the raw input row to xcopy (fuses the out[1]=x pass-through)
template<int COPYX>
__global__ __launch_bounds__(256) void ln_kernel(
    const float* __restrict__ x, const float* __restrict__ g,
    const float* __restrict__ b, short* __restrict__ out,
    float* __restrict__ xcopy)
{
  int row  = blockIdx.x * 4 + (threadIdx.x >> 6);
  int lane = threadIdx.x & 63;
  const float* xr = x + (size_t)row * 512 + lane * 8;
  f32x4 v0 = *(const f32x4*)(xr);
  f32x4 v1 = *(const f32x4*)(xr + 4);
  float s  = (v0[0]+v0[1]+v0[2]+v0[3]) + (v1[0]+v1[1]+v1[2]+v1[3]);
  float sq = (v0[0]*v0[0]+v0[1]*v0[1]+v0[2]*v0[2]+v0[3]*v0[3])
           + (v1[0]*v1[0]+v1[1]*v1[1]+v1[2]*v1[2]+v1[3]*v1[3]);
  #pragma unroll
  for (int off = 1; off < 64; off <<= 1) {
    s  += __shfl_xor(s, off);
    sq += __shfl_xor(sq, off);
  }
  float mu  = s * (1.0f / 512.0f);
  float var = sq * (1.0f / 512.0f) - mu * mu;
  float rstd = rsqrtf(var + 1e-5f);
  f32x4 g0 = *(const f32x4*)(g + lane * 8);
  f32x4 g1 = *(const f32x4*)(g + lane * 8 + 4);
  f32x4 b0 = *(const f32x4*)(b + lane * 8);
  f32x4 b1 = *(const f32x4*)(b + lane * 8 + 4);
  float o[8];
  #pragma unroll
  for (int j = 0; j < 4; ++j) o[j]     = (v0[j] - mu) * rstd * g0[j] + b0[j];
  #pragma unroll
  for (int j = 0; j < 4; ++j) o[4 + j] = (v1[j] - mu) * rstd * g1[j] + b1[j];
  uint4 pk;
  pk.x = cvtpk(o[0], o[1]); pk.y = cvtpk(o[2], o[3]);
  pk.z = cvtpk(o[4], o[5]); pk.w = cvtpk(o[6], o[7]);
  *(uint4*)(out + (size_t)row * 512 + lane * 8) = pk;
  if (COPYX) {
    float* xc = xcopy + (size_t)row * 512 + lane * 8;
    *(f32x4*)(xc)     = v0;
    *(f32x4*)(xc + 4) = v1;
  }
}

// ---------------- layernorm, bf16 input (one row per wave) ----------------
__global__ __launch_bounds__(256) void ln_bf_kernel(
    const short* __restrict__ x, const float* __restrict__ g,
    const float* __restrict__ b, short* __restrict__ out)
{
  int row  = blockIdx.x * 4 + (threadIdx.x >> 6);
  int lane = threadIdx.x & 63;
  short8 raw = *(const short8*)(x + (size_t)row * 512 + lane * 8);
  float v[8];
  #pragma unroll
  for (int j = 0; j < 8; ++j) v[j] = bf2f(raw[j]);
  float s = 0.f, sq = 0.f;
  #pragma unroll
  for (int j = 0; j < 8; ++j) { s += v[j]; sq += v[j] * v[j]; }
  #pragma unroll
  for (int off = 1; off < 64; off <<= 1) {
    s  += __shfl_xor(s, off);
    sq += __shfl_xor(sq, off);
  }
  float mu  = s * (1.0f / 512.0f);
  float var = sq * (1.0f / 512.0f) - mu * mu;
  float rstd = rsqrtf(var + 1e-5f);
  f32x4 g0 = *(const f32x4*)(g + lane * 8);
  f32x4 g1 = *(const f32x4*)(g + lane * 8 + 4);
  f32x4 b0 = *(const f32x4*)(b + lane * 8);
  f32x4 b1 = *(const f32x4*)(b + lane * 8 + 4);
  float o[8];
  #pragma unroll
  for (int j = 0; j < 4; ++j) o[j]     = (v[j] - mu) * rstd * g0[j] + b0[j];
  #pragma unroll
  for (int j = 0; j < 4; ++j) o[4 + j] = (v[4+j] - mu) * rstd * g1[j] + b1[j];
  uint4 pk;
  pk.x = cvtpk(o[0], o[1]); pk.y = cvtpk(o[2], o[3]);
  pk.z = cvtpk(o[4], o[5]); pk.w = cvtpk(o[6], o[7]);
  *(uint4*)(out + (size_t)row * 512 + lane * 8) = pk;
}

// ---------------- GEMM: C[M,N] = A[M,K] * Bt[N,K]^T  (bf16 in, f32 acc) ----------------
// BM in {128, 64}, BN=128, BK=32. 3-buffer ring, prefetch depth 2, counted vmcnt.
// EPI: 0 plain->bf16 ; 2 +bias,GELU->bf16 ; 3 qkv (V cols -> vt via LDS transpose)
//      4 +bias+resid(f32)->bf16 ; 5 +bias+resid(bf16)->f32
template<int EPI, int BM, typename OutT>
__global__ __launch_bounds__(256) void gemm_bt_kernel(
    const short* __restrict__ A, const short* __restrict__ Bt,
    OutT* __restrict__ C, const float* __restrict__ bias,
    const float* __restrict__ resid, const short* __restrict__ residb,
    short* __restrict__ vt, int M, int N, int K)
{
  constexpr int MFR = BM / 32;
  constexpr int NFR = 4;
  constexpr int AI  = BM / 64;
  constexpr int BUF = BM * 32 + 128 * 32;
  __shared__ __align__(16) short smem[3 * BUF];

  int tid = threadIdx.x;
  int lane = tid & 63, wid = tid >> 6;
  int l16 = lane & 15, lq = lane >> 4;

  int gx = gridDim.x;
  int nwg = gx * gridDim.y;
  int orig = blockIdx.y * gx + blockIdx.x;
  int swz = (orig & 7) * (nwg >> 3) + (orig >> 3);
  int bn = swz % gx, bm = swz / gx;

  int wm = wid >> 1, wn = wid & 1;

  const short* gaP[AI];
  const short* gbP[2];
  #pragma unroll
  for (int i = 0; i < AI; ++i) {
    int gg = i * 4 + wid;
    gaP[i] = A + (size_t)(bm * BM + gg * 16 + l16) * K + lq * 8;
  }
  #pragma unroll
  for (int i = 0; i < 2; ++i) {
    int gg = i * 4 + wid;
    gbP[i] = Bt + (size_t)(bn * 128 + gg * 16 + l16) * K + lq * 8;
  }

  auto STAGE = [&](int bufi, int k0) {
    short* base = smem + bufi * BUF;
    #pragma unroll
    for (int i = 0; i < AI; ++i)
      gload_lds16(gaP[i] + k0, base + (i * 4 + wid) * 512);
    #pragma unroll
    for (int i = 0; i < 2; ++i)
      gload_lds16(gbP[i] + k0, base + BM * 32 + (i * 4 + wid) * 512);
  };

  f32x4 acc[MFR][NFR] = {};

  STAGE(0, 0);
  STAGE(1, 32);

  int nt = K >> 5;
  for (int t = 0; t < nt; ++t) {
    if (t + 1 < nt) {
      if constexpr (AI == 2) asm volatile("s_waitcnt vmcnt(4)" ::: "memory");
      else                   asm volatile("s_waitcnt vmcnt(3)" ::: "memory");
    } else {
      asm volatile("s_waitcnt vmcnt(0)" ::: "memory");
    }
    __builtin_amdgcn_s_barrier();
    __builtin_amdgcn_sched_barrier(0);
    if (t + 2 < nt) STAGE((t + 2) % 3, (t + 2) << 5);

    const short* base = smem + (t % 3) * BUF;
    short8 af[MFR], bfr[NFR];
    #pragma unroll
    for (int m = 0; m < MFR; ++m)
      af[m] = *(const short8*)(base + (wm * MFR + m) * 512 + lane * 8);
    #pragma unroll
    for (int n = 0; n < NFR; ++n)
      bfr[n] = *(const short8*)(base + BM * 32 + (wn * NFR + n) * 512 + lane * 8);
    __builtin_amdgcn_s_setprio(1);
    #pragma unroll
    for (int m = 0; m < MFR; ++m)
      #pragma unroll
      for (int n = 0; n < NFR; ++n)
        acc[m][n] = __builtin_amdgcn_mfma_f32_16x16x32_bf16(af[m], bfr[n], acc[m][n], 0, 0, 0);
    __builtin_amdgcn_s_setprio(0);
  }

  if (EPI == 3 && bn >= 8) {
    // ---- V columns: LDS transpose -> vt [bh][d][n], coalesced 16B stores ----
    __syncthreads();
    short* T = smem;
    #pragma unroll
    for (int m = 0; m < MFR; ++m)
      #pragma unroll
      for (int n = 0; n < NFR; ++n) {
        int c = wn * 64 + n * 16 + l16;
        #pragma unroll
        for (int r = 0; r < 4; ++r) {
          int rowl = wm * 64 + m * 16 + lq * 4 + r;
          T[c * 128 + (rowl ^ ((c & 7) << 4))] = f2bf(acc[m][n][r]);
        }
      }
    __syncthreads();
    int b2 = bm >> 4;
    int nnb = (bm & 15) * 128;
    int tn = tid & 15;
    #pragma unroll
    for (int c8 = 0; c8 < 8; ++c8) {
      int c = c8 * 16 + (tid >> 4);
      short8 v = *(const short8*)(T + c * 128 + ((tn * 8) ^ ((c & 7) << 4)));
      if (tn & 1) {
        short8 w;
        #pragma unroll
        for (int j = 0; j < 8; ++j) w[j] = v[j ^ 4];
        v = w;
      }
      int c2 = bn * 128 + c - 1024;
      int bh = b2 * 8 + (c2 >> 6);
      int d  = c2 & 63;
      *(short8*)(vt + ((size_t)(bh * 64 + d)) * 2048 + nnb + tn * 8) = v;
    }
    return;
  }

  float bv[NFR];
  #pragma unroll
  for (int n = 0; n < NFR; ++n)
    bv[n] = (EPI == 0 || EPI == 3) ? 0.0f : bias[bn * 128 + (wn * NFR + n) * 16 + l16];

  #pragma unroll
  for (int m = 0; m < MFR; ++m) {
    #pragma unroll
    for (int r = 0; r < 4; ++r) {
      int row = bm * BM + (wm * MFR + m) * 16 + lq * 4 + r;
      #pragma unroll
      for (int n = 0; n < NFR; ++n) {
        int col = bn * 128 + (wn * NFR + n) * 16 + l16;
        float v = acc[m][n][r];
        if (EPI == 2 || EPI == 4 || EPI == 5) v += bv[n];
        if (EPI == 2) v = gelu_fast(v);
        if (EPI == 4) v += resid[(size_t)row * N + col];
        if (EPI == 5) v += bf2f(residb[(size_t)row * N + col]);
        if constexpr (sizeof(OutT) == 2)
          ((short*)C)[(size_t)row * N + col] = f2bf(v);
        else
          ((float*)C)[(size_t)row * N + col] = v;
      }
    }
  }
}

// ---------------- fused flash attention, split-KV (LSA diag mask) ----------------
// r5-measured-best staged structure; each block handles 1024 keys (slice 0/1).
// Fixed m=0 softmax => slice partials are PURE SUMS: O_s, l_s; combined later.
// Swapped-operand S^T = mfma(K,Q); in-register softmax; cvt_pk + butterfly -> PV.
__global__ __launch_bounds__(256, 2) void attn_kernel(
    const short* __restrict__ qkv, const short* __restrict__ vt,
    const float* __restrict__ temp_ptr,
    short* __restrict__ Op0, short* __restrict__ Op1, float* __restrict__ Lbuf)
{
  __shared__ __align__(16) short smem[16384];  // Ks[2][4096] | Vs[2][4096]

  int tid = threadIdx.x;
  int lane = tid & 63, wid = tid >> 6;
  int l16 = lane & 15, lq = lane >> 4;
  int hi = lq >> 1, lq0 = lq & 1;

  int orig = blockIdx.y * 16 + blockIdx.x;     // nwg = 1024
  int swz = (orig & 7) * 128 + (orig >> 3);
  int qb = swz & 15;
  int rr = swz >> 4;            // 0..63
  int bh = rr & 31, slice = rr >> 5;
  int b = bh >> 3, h = bh & 7;

  const short* qbase = qkv + (size_t)b * 2048 * 1536 + h * 64;
  const short* kbase = qbase + 512;
  const short* vbase = vt + (size_t)bh * 64 * 2048;
  int kslice = slice * 1024;

  float scale = __expf(temp_ptr[0]) * 1.44269504f;
  int q0 = qb * 128 + wid * 32;

  short8 qfrag[2][2];
  #pragma unroll
  for (int qf = 0; qf < 2; ++qf) {
    int qrow = q0 + qf * 16 + l16;
    #pragma unroll
    for (int c = 0; c < 2; ++c) {
      short8 raw = *(const short8*)(qbase + (size_t)qrow * 1536 + c * 32 + lq * 8);
      short8 sc;
      #pragma unroll
      for (int j = 0; j < 8; ++j) sc[j] = f2bf(bf2f(raw[j]) * scale);
      qfrag[qf][c] = sc;
    }
  }

  f32x4 accO[2][4] = {};
  float l[2] = {0.f, 0.f};

  auto STAGE = [&](int bufi, int k0) {
    #pragma unroll
    for (int i = 0; i < 2; ++i) {
      int w16 = i * 256 + tid;
      int sub = w16 >> 7;
      int cc  = (w16 >> 6) & 1;
      int lq2 = (w16 >> 4) & 3;
      int l2  = w16 & 15;
      const short* srcK = kbase + (size_t)(k0 + sub * 16 + l2) * 1536 + cc * 32 + lq2 * 8;
      gload_lds16(srcK, smem + bufi * 4096 + (i * 4 + wid) * 512);
      const short* srcV = vbase + (size_t)(sub * 16 + l2) * 2048 + k0 + cc * 32 + lq2 * 8;
      gload_lds16(srcV, smem + 8192 + bufi * 4096 + (i * 4 + wid) * 512);
    }
  };

  STAGE(0, kslice);
  asm volatile("s_waitcnt vmcnt(0)");
  __syncthreads();

  for (int t = 0; t < 16; ++t) {
    int cur = t & 1;
    int k0 = kslice + t * 64;
    if (t + 1 < 16) STAGE(cur ^ 1, k0 + 64);

    const short* kls = smem + cur * 4096;
    const short* vls = smem + 8192 + cur * 4096;

    f32x4 accS[2][4] = {};
    #pragma unroll
    for (int s = 0; s < 4; ++s) {
      short8 kf0 = *(const short8*)(kls + (s * 2 + 0) * 512 + lane * 8);
      short8 kf1 = *(const short8*)(kls + (s * 2 + 1) * 512 + lane * 8);
      #pragma unroll
      for (int qf = 0; qf < 2; ++qf) {
        accS[qf][s] = __builtin_amdgcn_mfma_f32_16x16x32_bf16(kf0, qfrag[qf][0], accS[qf][s], 0, 0, 0);
        accS[qf][s] = __builtin_amdgcn_mfma_f32_16x16x32_bf16(kf1, qfrag[qf][1], accS[qf][s], 0, 0, 0);
      }
    }

    if ((q0 & ~63) == k0) {
      #pragma unroll
      for (int qf = 0; qf < 2; ++qf) {
        int qg = q0 + qf * 16 + l16;
        #pragma unroll
        for (int s = 0; s < 4; ++s)
          #pragma unroll
          for (int r = 0; r < 4; ++r)
            if (k0 + s * 16 + lq * 4 + r == qg) accS[qf][s][r] = -30000.f;
      }
    }

    short8 pa[2][2];
    #pragma unroll
    for (int qf = 0; qf < 2; ++qf) {
      float sum = 0.f;
      unsigned W[4][2];
      #pragma unroll
      for (int s = 0; s < 4; ++s) {
        float p0 = exp2_hw(accS[qf][s][0]);
        float p1 = exp2_hw(accS[qf][s][1]);
        float p2 = exp2_hw(accS[qf][s][2]);
        float p3 = exp2_hw(accS[qf][s][3]);
        sum += (p0 + p1) + (p2 + p3);
        W[s][0] = cvtpk(p0, p1);
        W[s][1] = cvtpk(p2, p3);
      }
      sum += __shfl_xor(sum, 16);
      sum += __shfl_xor(sum, 32);
      l[qf] += sum;

      unsigned K0[2], S0[2], K2[2], S2[2], R0[2], R2[2];
      #pragma unroll
      for (int w = 0; w < 2; ++w) {
        K0[w] = hi ? W[1][w] : W[0][w];
        S0[w] = hi ? W[0][w] : W[1][w];
        K2[w] = hi ? W[3][w] : W[2][w];
        S2[w] = hi ? W[2][w] : W[3][w];
      }
      #pragma unroll
      for (int w = 0; w < 2; ++w) {
        R0[w] = (unsigned)__shfl_xor((int)S0[w], 32);
        R2[w] = (unsigned)__shfl_xor((int)S2[w], 32);
      }
      bool sw = (hi != lq0);
      unsigned FA[2], FB[2], sA[2], sB[2], GA[2], GB[2];
      #pragma unroll
      for (int w = 0; w < 2; ++w) {
        sA[w] = sw ? K0[w] : R0[w];  FA[w] = sw ? R0[w] : K0[w];
        sB[w] = sw ? K2[w] : R2[w];  FB[w] = sw ? R2[w] : K2[w];
      }
      #pragma unroll
      for (int w = 0; w < 2; ++w) {
        GA[w] = (unsigned)__shfl_xor((int)sA[w], 16);
        GB[w] = (unsigned)__shfl_xor((int)sB[w], 16);
      }
      union { unsigned u[4]; short8 s8; } p0u, p1u;
      p0u.u[0] = FA[0]; p0u.u[1] = FA[1]; p0u.u[2] = GA[0]; p0u.u[3] = GA[1];
      p1u.u[0] = FB[0]; p1u.u[1] = FB[1]; p1u.u[2] = GB[0]; p1u.u[3] = GB[1];
      pa[qf][0] = p0u.s8;
      pa[qf][1] = p1u.s8;
    }

    short8 vfr[4][2];
    #pragma unroll
    for (int d = 0; d < 4; ++d) {
      vfr[d][0] = *(const short8*)(vls + (d * 2 + 0) * 512 + lane * 8);
      vfr[d][1] = *(const short8*)(vls + (d * 2 + 1) * 512 + lane * 8);
    }
    #pragma unroll
    for (int qf = 0; qf < 2; ++qf)
      #pragma unroll
      for (int d = 0; d < 4; ++d) {
        accO[qf][d] = __builtin_amdgcn_mfma_f32_16x16x32_bf16(vfr[d][0], pa[qf][0], accO[qf][d], 0, 0, 0);
        accO[qf][d] = __builtin_amdgcn_mfma_f32_16x16x32_bf16(vfr[d][1], pa[qf][1], accO[qf][d], 0, 0, 0);
      }

    __syncthreads();
  }

  // ---- epilogue: raw partial O (no divide) + l per q-row ----
  short* op = slice ? Op1 : Op0;
  #pragma unroll
  for (int qf = 0; qf < 2; ++qf) {
    int qg = q0 + qf * 16 + l16;
    if (lq == 0) Lbuf[(size_t)(slice * 32 + bh) * 2048 + qg] = l[qf];
    size_t rowoff = (size_t)(b * 2048 + qg) * 512 + h * 64;
    #pragma unroll
    for (int d = 0; d < 4; ++d) {
      unsigned w0 = cvtpk(accO[qf][d][0], accO[qf][d][1]);
      unsigned w1 = cvtpk(accO[qf][d][2], accO[qf][d][3]);
      uint2 pk; pk.x = w0; pk.y = w1;
      *(uint2*)(op + rowoff + d * 16 + lq * 4) = pk;
    }
  }
}

// ---------------- split-KV combine: out = (O0+O1)/(l0+l1) ----------------
__global__ __launch_bounds__(256) void attn_combine_kernel(
    const short* __restrict__ Op0, const short* __restrict__ Op1,
    const float* __restrict__ Lbuf, short* __restrict__ out)
{
  int idx = blockIdx.x * 256 + threadIdx.x;    // one per 8 elems
  size_t e = (size_t)idx * 8;
  int row = (int)(e >> 9);                      // b*2048 + q
  int col = (int)(e & 511);
  int b = row >> 11, q = row & 2047;
  int bh = b * 8 + (col >> 6);
  float l0 = Lbuf[(size_t)bh * 2048 + q];
  float l1 = Lbuf[(size_t)(32 + bh) * 2048 + q];
  float inv = rcp_hw(l0 + l1);
  short8 a = *(const short8*)(Op0 + e);
  short8 c = *(const short8*)(Op1 + e);
  float o[8];
  #pragma unroll
  for (int j = 0; j < 8; ++j) o[j] = (bf2f(a[j]) + bf2f(c[j])) * inv;
  uint4 pk;
  pk.x = cvtpk(o[0], o[1]); pk.y = cvtpk(o[2], o[3]);
  pk.z = cvtpk(o[4], o[5]); pk.w = cvtpk(o[6], o[7]);
  *(uint4*)(out + e) = pk;
}

// ---------------- launcher ----------------
extern "C" void kernel_launch(void* const* d_in, const int* in_sizes, int n_in,
                              void* d_out, int out_size, void* d_ws, size_t ws_size,
                              hipStream_t stream)
{
  const float* x    = (const float*)d_in[0];
  const float* ln1g = (const float*)d_in[1];
  const float* ln1b = (const float*)d_in[2];
  const float* Wqkv = (const float*)d_in[3];
  const float* temp = (const float*)d_in[4];
  const float* Wo   = (const float*)d_in[5];
  const float* bo   = (const float*)d_in[6];
  const float* ln2g = (const float*)d_in[7];
  const float* ln2b = (const float*)d_in[8];
  const float* W1   = (const float*)d_in[9];
  const float* b1   = (const float*)d_in[10];
  const float* W2   = (const float*)d_in[11];
  const float* b2   = (const float*)d_in[12];
  float* out = (float*)d_out;

  char* ws = (char*)d_ws;
  short* wqkv_t = (short*)(ws);                    // [1536][512] bf16; dead after qkv GEMM
  float* lpart  = (float*)(ws);                    //   reuse: l partials [2][32][2048] f32
  short* wo_t   = (short*)(ws + 1572864);          // [512][512]
  short* w1_t   = (short*)(ws + 2097152);          // [2048][512]
  short* w2_t   = (short*)(ws + 4194304);          // [512][2048]
  short* h      = (short*)(ws + 6291456);          // [8192][512] bf16 (LN out; O-partial slice1 during attn)
  short* qkv    = (short*)(ws + 14680064);         // [8192][1536] bf16
  short* attn   = (short*)(ws + 39845888);         // [8192][512] bf16 (O-partial slice0, then combined)
  short* ybf    = (short*)(ws + 48234496);         // [8192][512] bf16 (after attn; overlays vt)
  short* vt     = (short*)(ws + 48234496);         // [32][64][2048] bf16 (dead once ybf written)
  short* t      = (short*)(ws + 14680064);         // [8192][2048] bf16 (reuses qkv)
  // ws high-water: 65,011,712 bytes (unchanged)

  const int M = 8192;

  transpose_bf16_kernel<<<dim3(1536 / 32, 512 / 32),  256, 0, stream>>>(Wqkv, wqkv_t, 512, 1536);
  transpose_bf16_kernel<<<dim3(512 / 32, 512 / 32),   256, 0, stream>>>(Wo,   wo_t,   512, 512);
  transpose_bf16_kernel<<<dim3(2048 / 32, 512 / 32),  256, 0, stream>>>(W1,   w1_t,   512, 2048);
  transpose_bf16_kernel<<<dim3(512 / 32, 2048 / 32),  256, 0, stream>>>(W2,   w2_t,   2048, 512);

  // LN1 + fused x -> out[1] copy
  ln_kernel<1><<<M / 4, 256, 0, stream>>>(x, ln1g, ln1b, h, out + (size_t)M * 512);

  gemm_bt_kernel<3, 128, short><<<dim3(1536 / 128, M / 128), 256, 0, stream>>>(
      h, wqkv_t, qkv, nullptr, nullptr, nullptr, vt, M, 1536, 512);

  // split-KV attention: slice0 -> attn, slice1 -> h, l -> lpart (overlays wqkv_t)
  attn_kernel<<<dim3(16, 64), 256, 0, stream>>>(qkv, vt, temp, attn, h, lpart);
  attn_combine_kernel<<<M * 512 / 8 / 256, 256, 0, stream>>>(attn, h, lpart, attn);

  gemm_bt_kernel<4, 64, short><<<dim3(512 / 128, M / 64), 256, 0, stream>>>(
      attn, wo_t, ybf, bo, x, nullptr, nullptr, M, 512, 512);

  ln_bf_kernel<<<M / 4, 256, 0, stream>>>(ybf, ln2g, ln2b, h);

  gemm_bt_kernel<2, 128, short><<<dim3(2048 / 128, M / 128), 256, 0, stream>>>(
      h, w1_t, t, b1, nullptr, nullptr, nullptr, M, 2048, 512);

  gemm_bt_kernel<5, 64, float><<<dim3(512 / 128, M / 64), 256, 0, stream>>>(
      t, w2_t, out, b2, nullptr, ybf, nullptr, M, 512, 2048);
}